// Round 12
// baseline (966.683 us; speedup 1.0000x reference)
//
#include <hip/hip_runtime.h>
#include <hip/hip_bf16.h>
#include <cstdint>

// Problem constants
#define MTOT 131072     // B*N = 4*32768 rows
#define MC2  65536      // rows per pair-chunk (2 batches)
#define MCH  32768      // rows per batch
#define HDIM 512
#define PLSTR 65600     // partial-plane stride in f32: 64K rows + 64 pad
                        // (breaks power-of-2 HBM channel aliasing; 256B-aligned)

typedef _Float16 f16x8 __attribute__((ext_vector_type(8)));
typedef _Float16 f16x4 __attribute__((ext_vector_type(4)));
typedef unsigned short u16x8 __attribute__((ext_vector_type(8)));
typedef unsigned short u16x4 __attribute__((ext_vector_type(4)));
typedef float    f32x4 __attribute__((ext_vector_type(4)));

__device__ __forceinline__ float bf2f(unsigned short u) {
  return __uint_as_float(((unsigned)u) << 16);
}

// ---- dtype-adaptive scalar input load: isbf=1 -> bf16, else f32 ----
__device__ __forceinline__ float ldin(const void* p, long i, int isbf) {
  if (isbf) return bf2f(((const unsigned short*)p)[i]);
  return ((const float*)p)[i];
}

// ---- async global->LDS, 16B per lane (deposit = wave-uniform base + lane*16) ----
__device__ __forceinline__ void load_lds16(const void* g, void* lds) {
  __builtin_amdgcn_global_load_lds(
      (const __attribute__((address_space(1))) void*)(unsigned long long)(uintptr_t)g,
      (__attribute__((address_space(3))) void*)(unsigned int)(uintptr_t)lds,
      16, 0, 0);
}

// ---- detect input dtype from trunk_balpha (== ones) ----
__global__ void detect_k(const unsigned* __restrict__ balpha, int* __restrict__ flag) {
  if (threadIdx.x == 0) flag[0] = (balpha[0] == 0x3F803F80u) ? 1 : 0;
}

// ---- alpha/beta: z @ Wa^T + ba  for 7 layers (trunk0-3, head xyz/rgb/opacity).
__global__ __launch_bounds__(256)
void prep_ab(const void* __restrict__ z,
             const void* __restrict__ twa, const void* __restrict__ tba,
             const void* __restrict__ twb, const void* __restrict__ tbb,
             const void* __restrict__ hwa, const void* __restrict__ hba,
             const void* __restrict__ hwb, const void* __restrict__ hbb,
             const int* __restrict__ flag,
             float* __restrict__ alphas, float* __restrict__ betas) {
  const int isbf = flag[0];
  const int bid = blockIdx.x;
  const int og = bid & 7, rest = bid >> 3;
  const int l = rest >> 3, p = (rest >> 2) & 1, b = rest & 3;
  __shared__ float zs[256];
  zs[threadIdx.x] = ldin(z, b * 256 + threadIdx.x, isbf);
  __syncthreads();
  const void *Wsrc, *bsrc;
  long wofs, bofs;
  if (l < 4) {
    Wsrc = (p ? twb : twa); wofs = (long)l * 512 * 256;
    bsrc = (p ? tbb : tba); bofs = l * 512;
  } else {
    const int h = (l == 6) ? 3 : (l - 4);   // heads: xyz=0, rgb=1, opacity=3 (scale dead)
    Wsrc = (p ? hwb : hwa); wofs = (long)h * 512 * 256;
    bsrc = (p ? hbb : hba); bofs = h * 512;
  }
  const int o = og * 64 + (threadIdx.x >> 2);
  const int kq = threadIdx.x & 3;
  float s = 0.f;
  if (isbf) {
    const unsigned short* wp = (const unsigned short*)Wsrc + wofs + (long)o * 256 + kq * 64;
#pragma unroll
    for (int g = 0; g < 8; g++) {
      u16x8 v = *(const u16x8*)(wp + g * 8);
#pragma unroll
      for (int j = 0; j < 8; j++) s += zs[kq * 64 + g * 8 + j] * bf2f(v[j]);
    }
  } else {
    const float* wp = (const float*)Wsrc + wofs + (long)o * 256 + kq * 64;
#pragma unroll
    for (int g = 0; g < 16; g++) {
      f32x4 v = *(const f32x4*)(wp + g * 4);
#pragma unroll
      for (int j = 0; j < 4; j++) s += zs[kq * 64 + g * 4 + j] * v[j];
    }
  }
  s += __shfl_xor(s, 1, 64);
  s += __shfl_xor(s, 2, 64);
  if (kq == 0) {
    float* dst = (p ? betas : alphas) + (l * 4 + b) * 512;
    dst[o] = s + ldin(bsrc, bofs + o, isbf);
  }
}

// ---- Wmod[l][b][o][k] = f16( W[l][o][k] * alpha[l][b][k] ) ----
__global__ void wmod_k(const void* __restrict__ tw, const void* __restrict__ hw,
                       const int* __restrict__ flag,
                       const float* __restrict__ alphas, _Float16* __restrict__ wmod) {
  const int isbf = flag[0];
  const long t = (long)blockIdx.x * 256 + threadIdx.x;
  const long idx = t * 8;
  const int l   = (int)(idx >> 20);
  const long r0 = idx & ((1 << 20) - 1);
  const int b   = (int)(r0 >> 18);
  const int o   = (int)((r0 >> 9) & 511);
  const int k0  = (int)(r0 & 511);
  const void* wsrc; long ofs;
  if (l < 4) { wsrc = tw; ofs = ((long)l << 18) + (o << 9) + k0; }
  else { const int h = (l == 6) ? 3 : (l - 4); wsrc = hw; ofs = ((long)h << 18) + (o << 9) + k0; }
  const float* al = alphas + (l * 4 + b) * 512 + k0;
  f32x4 a0 = *(const f32x4*)(al);
  f32x4 a1 = *(const f32x4*)(al + 4);
  f16x8 d;
  if (isbf) {
    u16x8 w8 = *(const u16x8*)((const unsigned short*)wsrc + ofs);
#pragma unroll
    for (int j = 0; j < 4; j++) d[j] = (_Float16)(bf2f(w8[j]) * a0[j]);
#pragma unroll
    for (int j = 0; j < 4; j++) d[4 + j] = (_Float16)(bf2f(w8[4 + j]) * a1[j]);
  } else {
    f32x4 w0 = *(const f32x4*)((const float*)wsrc + ofs);
    f32x4 w1 = *(const f32x4*)((const float*)wsrc + ofs + 4);
#pragma unroll
    for (int j = 0; j < 4; j++) d[j] = (_Float16)(w0[j] * a0[j]);
#pragma unroll
    for (int j = 0; j < 4; j++) d[4 + j] = (_Float16)(w1[j] * a1[j]);
  }
  *(f16x8*)(wmod + ((long)(l * 4 + b) << 18) + (o << 9) + k0) = d;
}

// ---- pack X[m][128] = [pt_feat(64) | onehots(9) | zeros] for one pair-chunk ----
__global__ __launch_bounds__(256)
void pack_x(const void* __restrict__ pt, const void* __restrict__ oh,
            long pt_ofs, long oh_ofs, const int* __restrict__ flag,
            _Float16* __restrict__ X) {
  const int isbf = flag[0];
  const int m = blockIdx.x * 8 + (threadIdx.x >> 5);
  const int c5 = threadIdx.x & 31;
  f16x4 d;
  if (c5 < 16) {
    if (isbf) {
      u16x4 v = *(const u16x4*)((const unsigned short*)pt + pt_ofs + (long)m * 64 + c5 * 4);
#pragma unroll
      for (int j = 0; j < 4; j++) d[j] = (_Float16)bf2f(v[j]);
    } else {
      f32x4 v = *(const f32x4*)((const float*)pt + pt_ofs + (long)m * 64 + c5 * 4);
#pragma unroll
      for (int j = 0; j < 4; j++) d[j] = (_Float16)v[j];
    }
  } else {
#pragma unroll
    for (int j = 0; j < 4; j++) {
      const int c = c5 * 4 + j;
      d[j] = (c < 73) ? (_Float16)ldin(oh, oh_ofs + (long)m * 9 + (c - 64), isbf) : (_Float16)0.f;
    }
  }
  *(f16x4*)(X + (long)m * 128 + c5 * 4) = d;
}

// ---- pack Wc[512][128] = [fc1_w(64) | fcma_w(9) | zeros], fc1 bias -> fp32 ----
__global__ void pack_wc(const void* __restrict__ fc1w, const void* __restrict__ fcmaw,
                        const void* __restrict__ fc1b, const int* __restrict__ flag,
                        _Float16* __restrict__ Wc, float* __restrict__ fb32) {
  const int isbf = flag[0];
  const int o = blockIdx.x, c = threadIdx.x;
  float v = 0.f;
  if (c < 64)      v = ldin(fc1w, o * 64 + c, isbf);
  else if (c < 73) v = ldin(fcmaw, o * 9 + c - 64, isbf);
  Wc[o * 128 + c] = (_Float16)v;
  if (c == 0) fb32[o] = ldin(fc1b, o, isbf);
}

// ---- convert head projection vectors + out biases to fp32 ----
__global__ void conv_small(const void* __restrict__ owx, const void* __restrict__ owr,
                           const void* __restrict__ owo, const void* __restrict__ obx,
                           const void* __restrict__ obr, const void* __restrict__ obo,
                           const int* __restrict__ flag, float* __restrict__ dst) {
  const int t = blockIdx.x * 256 + threadIdx.x;
  if (t >= 3591) return;
  const int isbf = flag[0];
  float v;
  if (t < 1536)      v = ldin(owx, t, isbf);
  else if (t < 3072) v = ldin(owr, t - 1536, isbf);
  else if (t < 3584) v = ldin(owo, t - 3072, isbf);
  else if (t < 3587) v = ldin(obx, t - 3584, isbf);
  else if (t < 3590) v = ldin(obr, t - 3587, isbf);
  else               v = ldin(obo, 0, isbf);
  dst[t] = v;
}

// ---- fc1 GEMM (K=128): proven 128x128 single-barrier double-buffered kernel ----
__global__ __launch_bounds__(256)
void gemm_k(const _Float16* __restrict__ A, int lda, int K,
            const _Float16* __restrict__ Wb, int ldb, long wstride,
            const float* __restrict__ biasb, int bstride,
            _Float16* __restrict__ C) {
  __shared__ __align__(16) short As[2 * 128 * 32];
  __shared__ __align__(16) short Bs[2 * 128 * 32];
  const int tid = threadIdx.x;
  const int wave = tid >> 6, lane = tid & 63;
  const int zr = blockIdx.z * MCH;
  const int m0 = blockIdx.x * 128;
  const int n0 = blockIdx.y * 128;
  const _Float16* W = Wb + (long)blockIdx.z * wstride;
  const float* bias = biasb + blockIdx.z * bstride;

  const int l4 = lane >> 2;
  const int sw4 = (lane & 3) ^ (l4 & 3);
  const _Float16* aA = A + (long)(zr + m0 + wave * 32 + l4) * lda + sw4 * 8;
  const _Float16* aB = W + (long)(n0 + wave * 32 + l4) * ldb + sw4 * 8;
  short* dA0 = &As[(wave * 32) * 32];
  short* dA1 = &As[(wave * 32 + 16) * 32];
  short* dB0 = &Bs[(wave * 32) * 32];
  short* dB1 = &Bs[(wave * 32 + 16) * 32];

  const int wm = wave >> 1, wn = wave & 1;
  const int fr = lane & 15, fq = lane >> 4;
  const int sq = (fq ^ (fr & 3)) * 8;

  f32x4 acc[4][4] = {};

  load_lds16(aA, dA0);
  load_lds16(aA + 16 * (long)lda, dA1);
  load_lds16(aB, dB0);
  load_lds16(aB + 16 * (long)ldb, dB1);

  const int nIter = K >> 5;
  for (int k = 0; k < nIter; k++) {
    const int cur = (k & 1) << 12;
    __syncthreads();
    if (k + 1 < nIter) {
      const int nxt = ((k + 1) & 1) << 12;
      const long ko = (long)(k + 1) * 32;
      load_lds16(aA + ko, dA0 + nxt);
      load_lds16(aA + ko + 16 * (long)lda, dA1 + nxt);
      load_lds16(aB + ko, dB0 + nxt);
      load_lds16(aB + ko + 16 * (long)ldb, dB1 + nxt);
    }
    f16x8 af[4], bfv[4];
#pragma unroll
    for (int i = 0; i < 4; i++)
      af[i] = *(const f16x8*)&As[cur + (wm * 64 + i * 16 + fr) * 32 + sq];
#pragma unroll
    for (int j = 0; j < 4; j++)
      bfv[j] = *(const f16x8*)&Bs[cur + (wn * 64 + j * 16 + fr) * 32 + sq];
#pragma unroll
    for (int i = 0; i < 4; i++)
#pragma unroll
      for (int j = 0; j < 4; j++)
        acc[i][j] = __builtin_amdgcn_mfma_f32_16x16x32_f16(af[i], bfv[j], acc[i][j], 0, 0, 0);
  }

#pragma unroll
  for (int j = 0; j < 4; j++) {
    const int col = n0 + wn * 64 + j * 16 + fr;
    const float bv = bias[col];
#pragma unroll
    for (int i = 0; i < 4; i++) {
      const long row = (long)zr + m0 + wm * 64 + i * 16 + fq * 4;
#pragma unroll
      for (int r = 0; r < 4; r++) {
        float v = acc[i][j][r] + bv;
        v = v > 0.f ? v : 0.2f * v;
        C[(row + r) * HDIM + col] = (_Float16)v;
      }
    }
  }
}

// ==== 256x256 pipelined GEMM (K=512), v5 2-barrier schedule, templated epilogue ====
// R11 evidence: heads are epilogue-STALL-bound (48.5MB/67.5us = 0.72TB/s, not BW;
// epilogue adds only ~7us VALU-busy but ~22+us wall -> latency chains). The only
// latency chains are the per-iteration Pc[] global loads (4 x 96 per thread, each
// feeding FMA->shfl->store). v8 fix: (1) hoist the 12 P values into registers
// before the i-loop; (2) interleave the 4-level shfl butterflies across NOUTx4
// independent chains; (3) batch partial stores as f32x4 (96 sparse -> 24 wide).
#define BAR() asm volatile("s_barrier" ::: "memory")
#define VMC(n) asm volatile("s_waitcnt vmcnt(" #n ")" ::: "memory")
#define LGK0() do { asm volatile("s_waitcnt lgkmcnt(0)" ::: "memory"); \
                    __builtin_amdgcn_sched_barrier(0); } while (0)
#define PR1 __builtin_amdgcn_s_setprio(1)
#define PR0 __builtin_amdgcn_s_setprio(0)

template <int NOUT, int CBASE>
__global__ __launch_bounds__(512, 2)
void gemm256_t(const _Float16* __restrict__ A,
               const _Float16* __restrict__ Wb, long wstride,
               const float* __restrict__ biasb, int bstride,
               _Float16* __restrict__ C,
               const float* __restrict__ P,
               float* __restrict__ part) {
  __shared__ __align__(16) short As[2][16384];   // 2 x 256rows x 64 f16 = 64 KB
  __shared__ __align__(16) short Bs[2][16384];   // 64 KB
  const int tid = threadIdx.x;
  const int wave = tid >> 6, lane = tid & 63;
  // XCD-chunked swizzle (512 = 8 x 64, bijective)
  const int gsw = (blockIdx.x & 7) * 64 + (blockIdx.x >> 3);
  const int z = gsw >> 8;
  const int n0 = (gsw & 1) * 256;
  const int m0 = ((gsw >> 1) & 127) * 256;
  const long zr = (long)z * MCH;
  const _Float16* W = Wb + (long)z * wstride;
  const float* bias = biasb + z * bstride;

  const int srow = lane >> 3;
  const int schk = (lane & 7) ^ srow;
  const _Float16* gA = A + (zr + m0 + wave * 8 + srow) * 512L + schk * 8;
  const _Float16* gB = W + ((long)(n0 + wave * 8 + srow)) * 512L + schk * 8;
  short* lA = &As[0][0] + wave * 512;
  short* lB = &Bs[0][0] + wave * 512;

#define STGA(buf, t, j) load_lds16(gA + (t) * 64 + (j) * (64 * 512L), lA + (buf) * 16384 + (j) * 4096)
#define STGB(buf, t, j) load_lds16(gB + (t) * 64 + (j) * (64 * 512L), lB + (buf) * 16384 + (j) * 4096)

  const int fr = lane & 15, fq = lane >> 4;
  const int wm = wave >> 2, wn = wave & 3;
  const int c0 = (fq ^ (fr & 7)) * 8;
  const int c1 = c0 ^ 32;
  const int aB0 = (wm * 128 + fr) * 64;
  const int bB0 = (wn * 64 + fr) * 64;

  f16x8 aLo[4][2], aHi[4][2], bLo[2][2], bHi[2][2];
  f32x4 acc[8][4] = {};

#define RDAL(buf, i) { aLo[i][0] = *(const f16x8*)&As[buf][aB0 + (i) * 1024 + c0]; \
                       aLo[i][1] = *(const f16x8*)&As[buf][aB0 + (i) * 1024 + c1]; }
#define RDAH(buf, i) { aHi[i][0] = *(const f16x8*)&As[buf][aB0 + ((i) + 4) * 1024 + c0]; \
                       aHi[i][1] = *(const f16x8*)&As[buf][aB0 + ((i) + 4) * 1024 + c1]; }
#define RDBL(buf, j) { bLo[j][0] = *(const f16x8*)&Bs[buf][bB0 + (j) * 1024 + c0]; \
                       bLo[j][1] = *(const f16x8*)&Bs[buf][bB0 + (j) * 1024 + c1]; }
#define RDBH(buf, j) { bHi[j][0] = *(const f16x8*)&Bs[buf][bB0 + ((j) + 2) * 1024 + c0]; \
                       bHi[j][1] = *(const f16x8*)&Bs[buf][bB0 + ((j) + 2) * 1024 + c1]; }
#define MMQ(AF, io, BF, jo) { \
  _Pragma("unroll") for (int il = 0; il < 4; il++) \
  _Pragma("unroll") for (int jl = 0; jl < 2; jl++) { \
    acc[(io) + il][(jo) + jl] = __builtin_amdgcn_mfma_f32_16x16x32_f16( \
        AF[il][0], BF[jl][0], acc[(io) + il][(jo) + jl], 0, 0, 0); \
    acc[(io) + il][(jo) + jl] = __builtin_amdgcn_mfma_f32_16x16x32_f16( \
        AF[il][1], BF[jl][1], acc[(io) + il][(jo) + jl], 0, 0, 0); } }

  STGB(0, 0, 0); STGB(0, 0, 1); STGB(0, 0, 2); STGB(0, 0, 3);
  STGA(0, 0, 0); STGA(0, 0, 1); STGA(0, 0, 2); STGA(0, 0, 3);
  STGB(1, 1, 0); STGB(1, 1, 1); STGB(1, 1, 2); STGB(1, 1, 3);
  STGA(1, 1, 0); STGA(1, 1, 1); STGA(1, 1, 2); STGA(1, 1, 3);
  VMC(8); BAR();

#pragma unroll
  for (int t = 0; t < 8; t++) {
    const int buf = t & 1;
    RDAL(buf, 0) RDAL(buf, 1) RDAL(buf, 2) RDAL(buf, 3)
    RDBL(buf, 0) RDBL(buf, 1)
    RDBH(buf, 0) RDBH(buf, 1)
    RDAH(buf, 0) RDAH(buf, 1) RDAH(buf, 2) RDAH(buf, 3)
    PR1; MMQ(aLo, 0, bLo, 0); MMQ(aLo, 0, bHi, 2); PR0;
    LGK0();
    BAR();
    if (t + 2 < 8) { STGB(buf, t + 2, 0); STGB(buf, t + 2, 1);
                     STGB(buf, t + 2, 2); STGB(buf, t + 2, 3);
                     STGA(buf, t + 2, 0); STGA(buf, t + 2, 1);
                     STGA(buf, t + 2, 2); STGA(buf, t + 2, 3); }
    PR1; MMQ(aHi, 4, bLo, 0); MMQ(aHi, 4, bHi, 2); PR0;
    if (t < 6) { VMC(8); } else if (t == 6) { VMC(0); }
    BAR();
  }

  float bv[4];
#pragma unroll
  for (int j = 0; j < 4; j++) bv[j] = bias[n0 + wn * 64 + j * 16 + fr];

  if constexpr (NOUT == 0) {
    // trunk epilogue: bias + LeakyReLU, f16 store, j-inner (write-merge)
#pragma unroll
    for (int i = 0; i < 8; i++) {
      const long row = zr + m0 + wm * 128 + i * 16 + fq * 4;
#pragma unroll
      for (int r = 0; r < 4; r++) {
        _Float16* cp = C + (row + r) * HDIM + n0 + wn * 64 + fr;
#pragma unroll
        for (int j = 0; j < 4; j++) {
          float v = acc[i][j][r] + bv[j];
          v = v > 0.f ? v : 0.2f * v;
          cp[j * 16] = (_Float16)v;
        }
      }
    }
  } else {
    // head epilogue v8: fused projection with HOISTED P registers,
    // interleaved shfl butterflies, f32x4 partial stores.
    const int slot = ((n0 >> 8) << 2) + wn;   // 0..7
    float pv[NOUT][4];
#pragma unroll
    for (int c = 0; c < NOUT; c++)
#pragma unroll
      for (int j = 0; j < 4; j++)
        pv[c][j] = P[c * 512 + n0 + wn * 64 + j * 16 + fr];
#pragma unroll
    for (int i = 0; i < 8; i++) {
      float sv[NOUT][4];   // [c][r]
#pragma unroll
      for (int r = 0; r < 4; r++) {
        float av[4];
#pragma unroll
        for (int j = 0; j < 4; j++) {
          float v = acc[i][j][r] + bv[j];
          av[j] = v > 0.f ? v : 0.2f * v;
        }
#pragma unroll
        for (int c = 0; c < NOUT; c++)
          sv[c][r] = av[0] * pv[c][0] + av[1] * pv[c][1]
                   + av[2] * pv[c][2] + av[3] * pv[c][3];
      }
      // 4-level butterfly over the 16 fr lanes; NOUT*4 independent chains
#pragma unroll
      for (int off = 1; off < 16; off <<= 1)
#pragma unroll
        for (int c = 0; c < NOUT; c++)
#pragma unroll
          for (int r = 0; r < 4; r++)
            sv[c][r] += __shfl_xor(sv[c][r], off, 64);
      if (fr == 0) {
        const long rowb = zr + m0 + wm * 128 + i * 16 + fq * 4;
#pragma unroll
        for (int c = 0; c < NOUT; c++) {
          f32x4 o4 = { sv[c][0], sv[c][1], sv[c][2], sv[c][3] };
          *(f32x4*)&part[(long)((CBASE + c) * 8 + slot) * PLSTR + rowb] = o4;
        }
      }
    }
  }
#undef STGA
#undef STGB
#undef RDAL
#undef RDAH
#undef RDBL
#undef RDBH
#undef MMQ
}

// ---- finalize: sum 8 padded-plane partial slots per (row, out), final nonlinearity ----
// ob = ow32+3584: obx=ob[0..2], obr=ob[3..5], obo=ob[6]
__global__ __launch_bounds__(256)
void fin_k(const float* __restrict__ part, const float* __restrict__ ob,
           const int* __restrict__ flag, void* __restrict__ outv, long row0) {
  const long row = (long)blockIdx.x * 256 + threadIdx.x;
  float s[7];
#pragma unroll
  for (int c = 0; c < 7; c++) {
    float acc = 0.f;
#pragma unroll
    for (int sl = 0; sl < 8; sl++) acc += part[(long)(c * 8 + sl) * PLSTR + row];
    s[c] = acc;
  }
  float v[10];
#pragma unroll
  for (int c = 0; c < 3; c++) v[c] = 1.f / (1.f + __expf(-(s[c] + ob[c]))) - 0.5f;
#pragma unroll
  for (int c = 0; c < 3; c++) v[3 + c] = s[3 + c] + ob[3 + c];
  v[6] = 1.0f; v[7] = 1.0f; v[8] = 1.0f;
  v[9] = 1.f / (1.f + __expf(-(s[6] + ob[6])));
  const long ro = (row0 + row) * 10;
  if (flag[0]) {
    __hip_bfloat16* o = (__hip_bfloat16*)outv + ro;
#pragma unroll
    for (int c = 0; c < 10; c++) o[c] = __float2bfloat16(v[c]);
  } else {
    float* o = (float*)outv + ro;
#pragma unroll
    for (int c = 0; c < 10; c++) o[c] = v[c];
  }
}

extern "C" void kernel_launch(void* const* d_in, const int* in_sizes, int n_in,
                              void* d_out, int out_size, void* d_ws, size_t ws_size,
                              hipStream_t stream) {
  const void* pt    = d_in[0];
  const void* oh    = d_in[1];
  const void* z     = d_in[2];
  const void* fc1w  = d_in[3];
  const void* fc1b  = d_in[4];
  const void* fcmaw = d_in[5];
  const void* tw    = d_in[6];
  const void* twa   = d_in[7];
  const void* tba   = d_in[8];
  const void* twb   = d_in[9];
  const void* tbb   = d_in[10];
  const void* hw    = d_in[11];
  const void* hwa   = d_in[12];
  const void* hba   = d_in[13];
  const void* hwb   = d_in[14];
  const void* hbb   = d_in[15];
  const void* owx   = d_in[16];
  const void* obx   = d_in[17];
  const void* owr   = d_in[18];
  const void* obr   = d_in[19];
  // d_in[20], d_in[21] (scale head out proj) unused: clip(x,1,1) == 1
  const void* owo   = d_in[22];
  const void* obo   = d_in[23];

  char* ws = (char*)d_ws;
  _Float16* g0    = (_Float16*)(ws + 0);             // 67,108,864  (MC2 x 512 f16)
  _Float16* g1    = (_Float16*)(ws + 67108864LL);    // 67,108,864
  _Float16* X     = (_Float16*)(ws + 67108864LL);    // aliases g1 (dead before trunk0 writes g1)
  _Float16* wmodp = (_Float16*)(ws + 134217728LL);   // 14,680,064
  _Float16* Wc    = (_Float16*)(ws + 148897792LL);   // 131,072
  float* alphas   = (float*)(ws + 149028864LL);      // 57,344
  float* betas    = (float*)(ws + 149086208LL);      // 57,344
  float* fb32     = (float*)(ws + 149143552LL);      // 2,048
  int*   dflag    = (int*)  (ws + 149145600LL);      // 64
  float* ow32     = (float*)(ws + 149145664LL);      // 14,364 (3591 f32)
  float* part     = (float*)(ws + 167772160LL);      // 16,793,600 (64 planes x PLSTR f32)

  detect_k<<<1, 64, 0, stream>>>((const unsigned*)tba, dflag);
  prep_ab<<<448, 256, 0, stream>>>(z, twa, tba, twb, tbb, hwa, hba, hwb, hbb, dflag, alphas, betas);
  wmod_k<<<3584, 256, 0, stream>>>(tw, hw, dflag, alphas, wmodp);
  pack_wc<<<512, 128, 0, stream>>>(fc1w, fcmaw, fc1b, dflag, Wc, fb32);
  conv_small<<<15, 256, 0, stream>>>(owx, owr, owo, obx, obr, obo, dflag, ow32);

  dim3 gg(MCH / 128, 4, 2), gb(256);
  for (int p = 0; p < 2; p++) {
    const long prow = (long)p * MC2;
    pack_x<<<MC2 / 8, 256, 0, stream>>>(pt, oh, prow * 64, prow * 9, dflag, X);
    // fc1 via zero-padded K=128 (cols 73..127 of X and Wc are 0); same W/bias for both z
    gemm_k<<<gg, gb, 0, stream>>>(X, 128, 128, Wc, 128, 0, fb32, 0, g0);
    // trunk 0..3 (ping-pong g0 <-> g1; ends in g0)
    _Float16* fin = g0; _Float16* fout = g1;
    for (int l = 0; l < 4; l++) {
      gemm256_t<0, 0><<<512, 512, 0, stream>>>(fin, wmodp + (long)(l * 4 + p * 2) * 262144, 262144,
                                               betas + (l * 4 + p * 2) * 512, 512, fout,
                                               nullptr, nullptr);
      _Float16* t = fin; fin = fout; fout = t;
    }
    // heads: fused GEMM+projection -> padded plane-major f32 partials
    gemm256_t<3, 0><<<512, 512, 0, stream>>>(fin, wmodp + (long)(4 * 4 + p * 2) * 262144, 262144,
                                             betas + (4 * 4 + p * 2) * 512, 512, nullptr,
                                             ow32, part);
    gemm256_t<3, 3><<<512, 512, 0, stream>>>(fin, wmodp + (long)(5 * 4 + p * 2) * 262144, 262144,
                                             betas + (5 * 4 + p * 2) * 512, 512, nullptr,
                                             ow32 + 1536, part);
    gemm256_t<1, 6><<<512, 512, 0, stream>>>(fin, wmodp + (long)(6 * 4 + p * 2) * 262144, 262144,
                                             betas + (6 * 4 + p * 2) * 512, 512, nullptr,
                                             ow32 + 3072, part);
    fin_k<<<MC2 / 256, 256, 0, stream>>>(part, ow32 + 3584, dflag, d_out, prow);
  }
}

// Round 14
// 830.139 us; speedup vs baseline: 1.1645x; 1.1645x over previous
//
#include <hip/hip_runtime.h>
#include <hip/hip_bf16.h>
#include <cstdint>

// Problem constants
#define MTOT 131072     // B*N = 4*32768 rows
#define MC2  65536      // rows per pair-chunk (2 batches)
#define MCH  32768      // rows per batch
#define HDIM 512
#define PLSTR 65600     // partial-plane stride in f32: 64K rows + 64 pad
                        // (breaks power-of-2 HBM channel aliasing; 256B-aligned)

typedef _Float16 f16x8 __attribute__((ext_vector_type(8)));
typedef _Float16 f16x4 __attribute__((ext_vector_type(4)));
typedef unsigned short u16x8 __attribute__((ext_vector_type(8)));
typedef unsigned short u16x4 __attribute__((ext_vector_type(4)));
typedef float    f32x4 __attribute__((ext_vector_type(4)));

__device__ __forceinline__ float bf2f(unsigned short u) {
  return __uint_as_float(((unsigned)u) << 16);
}

// ---- dtype-adaptive scalar input load: isbf=1 -> bf16, else f32 ----
__device__ __forceinline__ float ldin(const void* p, long i, int isbf) {
  if (isbf) return bf2f(((const unsigned short*)p)[i]);
  return ((const float*)p)[i];
}

// ---- async global->LDS, 16B per lane (deposit = wave-uniform base + lane*16) ----
__device__ __forceinline__ void load_lds16(const void* g, void* lds) {
  __builtin_amdgcn_global_load_lds(
      (const __attribute__((address_space(1))) void*)(unsigned long long)(uintptr_t)g,
      (__attribute__((address_space(3))) void*)(unsigned int)(uintptr_t)lds,
      16, 0, 0);
}

// ---- 16-lane (DPP row) sum on the VALU pipe, result in lane 0 of each row.
//      R13 fix: row_SHL (0x10N: lane i gets lane i+N) — R12 used row_shr which
//      accumulated into lane 15 while the writer was lane 0 (absmax 6.7).
//      bound_ctrl=true zero-fills out-of-row reads (correct for a sum).
__device__ __forceinline__ float dpp16_sum(float v) {
  int x = __float_as_int(v);
  v += __int_as_float(__builtin_amdgcn_update_dpp(0, x, 0x101, 0xF, 0xF, true)); // row_shl:1
  x = __float_as_int(v);
  v += __int_as_float(__builtin_amdgcn_update_dpp(0, x, 0x102, 0xF, 0xF, true)); // row_shl:2
  x = __float_as_int(v);
  v += __int_as_float(__builtin_amdgcn_update_dpp(0, x, 0x104, 0xF, 0xF, true)); // row_shl:4
  x = __float_as_int(v);
  v += __int_as_float(__builtin_amdgcn_update_dpp(0, x, 0x108, 0xF, 0xF, true)); // row_shl:8
  return v;
}

// ---- detect input dtype from trunk_balpha (== ones) ----
__global__ void detect_k(const unsigned* __restrict__ balpha, int* __restrict__ flag) {
  if (threadIdx.x == 0) flag[0] = (balpha[0] == 0x3F803F80u) ? 1 : 0;
}

// ---- alpha/beta: z @ Wa^T + ba  for 7 layers (trunk0-3, head xyz/rgb/opacity).
__global__ __launch_bounds__(256)
void prep_ab(const void* __restrict__ z,
             const void* __restrict__ twa, const void* __restrict__ tba,
             const void* __restrict__ twb, const void* __restrict__ tbb,
             const void* __restrict__ hwa, const void* __restrict__ hba,
             const void* __restrict__ hwb, const void* __restrict__ hbb,
             const int* __restrict__ flag,
             float* __restrict__ alphas, float* __restrict__ betas) {
  const int isbf = flag[0];
  const int bid = blockIdx.x;
  const int og = bid & 7, rest = bid >> 3;
  const int l = rest >> 3, p = (rest >> 2) & 1, b = rest & 3;
  __shared__ float zs[256];
  zs[threadIdx.x] = ldin(z, b * 256 + threadIdx.x, isbf);
  __syncthreads();
  const void *Wsrc, *bsrc;
  long wofs, bofs;
  if (l < 4) {
    Wsrc = (p ? twb : twa); wofs = (long)l * 512 * 256;
    bsrc = (p ? tbb : tba); bofs = l * 512;
  } else {
    const int h = (l == 6) ? 3 : (l - 4);   // heads: xyz=0, rgb=1, opacity=3 (scale dead)
    Wsrc = (p ? hwb : hwa); wofs = (long)h * 512 * 256;
    bsrc = (p ? hbb : hba); bofs = h * 512;
  }
  const int o = og * 64 + (threadIdx.x >> 2);
  const int kq = threadIdx.x & 3;
  float s = 0.f;
  if (isbf) {
    const unsigned short* wp = (const unsigned short*)Wsrc + wofs + (long)o * 256 + kq * 64;
#pragma unroll
    for (int g = 0; g < 8; g++) {
      u16x8 v = *(const u16x8*)(wp + g * 8);
#pragma unroll
      for (int j = 0; j < 8; j++) s += zs[kq * 64 + g * 8 + j] * bf2f(v[j]);
    }
  } else {
    const float* wp = (const float*)Wsrc + wofs + (long)o * 256 + kq * 64;
#pragma unroll
    for (int g = 0; g < 16; g++) {
      f32x4 v = *(const f32x4*)(wp + g * 4);
#pragma unroll
      for (int j = 0; j < 4; j++) s += zs[kq * 64 + g * 4 + j] * v[j];
    }
  }
  s += __shfl_xor(s, 1, 64);
  s += __shfl_xor(s, 2, 64);
  if (kq == 0) {
    float* dst = (p ? betas : alphas) + (l * 4 + b) * 512;
    dst[o] = s + ldin(bsrc, bofs + o, isbf);
  }
}

// ---- Wmod[l][b][o][k] = f16( W[l][o][k] * alpha[l][b][k] ) ----
__global__ void wmod_k(const void* __restrict__ tw, const void* __restrict__ hw,
                       const int* __restrict__ flag,
                       const float* __restrict__ alphas, _Float16* __restrict__ wmod) {
  const int isbf = flag[0];
  const long t = (long)blockIdx.x * 256 + threadIdx.x;
  const long idx = t * 8;
  const int l   = (int)(idx >> 20);
  const long r0 = idx & ((1 << 20) - 1);
  const int b   = (int)(r0 >> 18);
  const int o   = (int)((r0 >> 9) & 511);
  const int k0  = (int)(r0 & 511);
  const void* wsrc; long ofs;
  if (l < 4) { wsrc = tw; ofs = ((long)l << 18) + (o << 9) + k0; }
  else { const int h = (l == 6) ? 3 : (l - 4); wsrc = hw; ofs = ((long)h << 18) + (o << 9) + k0; }
  const float* al = alphas + (l * 4 + b) * 512 + k0;
  f32x4 a0 = *(const f32x4*)(al);
  f32x4 a1 = *(const f32x4*)(al + 4);
  f16x8 d;
  if (isbf) {
    u16x8 w8 = *(const u16x8*)((const unsigned short*)wsrc + ofs);
#pragma unroll
    for (int j = 0; j < 4; j++) d[j] = (_Float16)(bf2f(w8[j]) * a0[j]);
#pragma unroll
    for (int j = 0; j < 4; j++) d[4 + j] = (_Float16)(bf2f(w8[4 + j]) * a1[j]);
  } else {
    f32x4 w0 = *(const f32x4*)((const float*)wsrc + ofs);
    f32x4 w1 = *(const f32x4*)((const float*)wsrc + ofs + 4);
#pragma unroll
    for (int j = 0; j < 4; j++) d[j] = (_Float16)(w0[j] * a0[j]);
#pragma unroll
    for (int j = 0; j < 4; j++) d[4 + j] = (_Float16)(w1[j] * a1[j]);
  }
  *(f16x8*)(wmod + ((long)(l * 4 + b) << 18) + (o << 9) + k0) = d;
}

// ---- pack X[m][128] = [pt_feat(64) | onehots(9) | zeros] for one pair-chunk ----
__global__ __launch_bounds__(256)
void pack_x(const void* __restrict__ pt, const void* __restrict__ oh,
            long pt_ofs, long oh_ofs, const int* __restrict__ flag,
            _Float16* __restrict__ X) {
  const int isbf = flag[0];
  const int m = blockIdx.x * 8 + (threadIdx.x >> 5);
  const int c5 = threadIdx.x & 31;
  f16x4 d;
  if (c5 < 16) {
    if (isbf) {
      u16x4 v = *(const u16x4*)((const unsigned short*)pt + pt_ofs + (long)m * 64 + c5 * 4);
#pragma unroll
      for (int j = 0; j < 4; j++) d[j] = (_Float16)bf2f(v[j]);
    } else {
      f32x4 v = *(const f32x4*)((const float*)pt + pt_ofs + (long)m * 64 + c5 * 4);
#pragma unroll
      for (int j = 0; j < 4; j++) d[j] = (_Float16)v[j];
    }
  } else {
#pragma unroll
    for (int j = 0; j < 4; j++) {
      const int c = c5 * 4 + j;
      d[j] = (c < 73) ? (_Float16)ldin(oh, oh_ofs + (long)m * 9 + (c - 64), isbf) : (_Float16)0.f;
    }
  }
  *(f16x4*)(X + (long)m * 128 + c5 * 4) = d;
}

// ---- pack Wc[512][128] = [fc1_w(64) | fcma_w(9) | zeros], fc1 bias -> fp32 ----
__global__ void pack_wc(const void* __restrict__ fc1w, const void* __restrict__ fcmaw,
                        const void* __restrict__ fc1b, const int* __restrict__ flag,
                        _Float16* __restrict__ Wc, float* __restrict__ fb32) {
  const int isbf = flag[0];
  const int o = blockIdx.x, c = threadIdx.x;
  float v = 0.f;
  if (c < 64)      v = ldin(fc1w, o * 64 + c, isbf);
  else if (c < 73) v = ldin(fcmaw, o * 9 + c - 64, isbf);
  Wc[o * 128 + c] = (_Float16)v;
  if (c == 0) fb32[o] = ldin(fc1b, o, isbf);
}

// ---- convert head projection vectors + out biases to fp32 ----
__global__ void conv_small(const void* __restrict__ owx, const void* __restrict__ owr,
                           const void* __restrict__ owo, const void* __restrict__ obx,
                           const void* __restrict__ obr, const void* __restrict__ obo,
                           const int* __restrict__ flag, float* __restrict__ dst) {
  const int t = blockIdx.x * 256 + threadIdx.x;
  if (t >= 3591) return;
  const int isbf = flag[0];
  float v;
  if (t < 1536)      v = ldin(owx, t, isbf);
  else if (t < 3072) v = ldin(owr, t - 1536, isbf);
  else if (t < 3584) v = ldin(owo, t - 3072, isbf);
  else if (t < 3587) v = ldin(obx, t - 3584, isbf);
  else if (t < 3590) v = ldin(obr, t - 3587, isbf);
  else               v = ldin(obo, 0, isbf);
  dst[t] = v;
}

// ---- fc1 GEMM (K=128): proven 128x128 single-barrier double-buffered kernel ----
__global__ __launch_bounds__(256)
void gemm_k(const _Float16* __restrict__ A, int lda, int K,
            const _Float16* __restrict__ Wb, int ldb, long wstride,
            const float* __restrict__ biasb, int bstride,
            _Float16* __restrict__ C) {
  __shared__ __align__(16) short As[2 * 128 * 32];
  __shared__ __align__(16) short Bs[2 * 128 * 32];
  const int tid = threadIdx.x;
  const int wave = tid >> 6, lane = tid & 63;
  const int zr = blockIdx.z * MCH;
  const int m0 = blockIdx.x * 128;
  const int n0 = blockIdx.y * 128;
  const _Float16* W = Wb + (long)blockIdx.z * wstride;
  const float* bias = biasb + blockIdx.z * bstride;

  const int l4 = lane >> 2;
  const int sw4 = (lane & 3) ^ (l4 & 3);
  const _Float16* aA = A + (long)(zr + m0 + wave * 32 + l4) * lda + sw4 * 8;
  const _Float16* aB = W + (long)(n0 + wave * 32 + l4) * ldb + sw4 * 8;
  short* dA0 = &As[(wave * 32) * 32];
  short* dA1 = &As[(wave * 32 + 16) * 32];
  short* dB0 = &Bs[(wave * 32) * 32];
  short* dB1 = &Bs[(wave * 32 + 16) * 32];

  const int wm = wave >> 1, wn = wave & 1;
  const int fr = lane & 15, fq = lane >> 4;
  const int sq = (fq ^ (fr & 3)) * 8;

  f32x4 acc[4][4] = {};

  load_lds16(aA, dA0);
  load_lds16(aA + 16 * (long)lda, dA1);
  load_lds16(aB, dB0);
  load_lds16(aB + 16 * (long)ldb, dB1);

  const int nIter = K >> 5;
  for (int k = 0; k < nIter; k++) {
    const int cur = (k & 1) << 12;
    __syncthreads();
    if (k + 1 < nIter) {
      const int nxt = ((k + 1) & 1) << 12;
      const long ko = (long)(k + 1) * 32;
      load_lds16(aA + ko, dA0 + nxt);
      load_lds16(aA + ko + 16 * (long)lda, dA1 + nxt);
      load_lds16(aB + ko, dB0 + nxt);
      load_lds16(aB + ko + 16 * (long)ldb, dB1 + nxt);
    }
    f16x8 af[4], bfv[4];
#pragma unroll
    for (int i = 0; i < 4; i++)
      af[i] = *(const f16x8*)&As[cur + (wm * 64 + i * 16 + fr) * 32 + sq];
#pragma unroll
    for (int j = 0; j < 4; j++)
      bfv[j] = *(const f16x8*)&Bs[cur + (wn * 64 + j * 16 + fr) * 32 + sq];
#pragma unroll
    for (int i = 0; i < 4; i++)
#pragma unroll
      for (int j = 0; j < 4; j++)
        acc[i][j] = __builtin_amdgcn_mfma_f32_16x16x32_f16(af[i], bfv[j], acc[i][j], 0, 0, 0);
  }

#pragma unroll
  for (int j = 0; j < 4; j++) {
    const int col = n0 + wn * 64 + j * 16 + fr;
    const float bv = bias[col];
#pragma unroll
    for (int i = 0; i < 4; i++) {
      const long row = (long)zr + m0 + wm * 64 + i * 16 + fq * 4;
#pragma unroll
      for (int r = 0; r < 4; r++) {
        float v = acc[i][j][r] + bv;
        v = v > 0.f ? v : 0.2f * v;
        C[(row + r) * HDIM + col] = (_Float16)v;
      }
    }
  }
}

// ==== 256x256 pipelined GEMM (K=512), v5 2-barrier schedule, templated epilogue ====
// Head epilogue: fused projection; 16-lane reduction on the VALU pipe via DPP
// row_shl adds (R13: fixed direction — sum lands in lane fr==0, the writer).
// Theory under test: R11's 67.5us heads were DS-pipe-bound (384 wave shfls);
// DPP removes all DS traffic from the reduction.
#define BAR() asm volatile("s_barrier" ::: "memory")
#define VMC(n) asm volatile("s_waitcnt vmcnt(" #n ")" ::: "memory")
#define LGK0() do { asm volatile("s_waitcnt lgkmcnt(0)" ::: "memory"); \
                    __builtin_amdgcn_sched_barrier(0); } while (0)
#define PR1 __builtin_amdgcn_s_setprio(1)
#define PR0 __builtin_amdgcn_s_setprio(0)

template <int NOUT, int CBASE>
__global__ __launch_bounds__(512, 2)
void gemm256_t(const _Float16* __restrict__ A,
               const _Float16* __restrict__ Wb, long wstride,
               const float* __restrict__ biasb, int bstride,
               _Float16* __restrict__ C,
               const float* __restrict__ P,
               float* __restrict__ part) {
  __shared__ __align__(16) short As[2][16384];   // 2 x 256rows x 64 f16 = 64 KB
  __shared__ __align__(16) short Bs[2][16384];   // 64 KB
  const int tid = threadIdx.x;
  const int wave = tid >> 6, lane = tid & 63;
  // XCD-chunked swizzle (512 = 8 x 64, bijective)
  const int gsw = (blockIdx.x & 7) * 64 + (blockIdx.x >> 3);
  const int z = gsw >> 8;
  const int n0 = (gsw & 1) * 256;
  const int m0 = ((gsw >> 1) & 127) * 256;
  const long zr = (long)z * MCH;
  const _Float16* W = Wb + (long)z * wstride;
  const float* bias = biasb + z * bstride;

  const int srow = lane >> 3;
  const int schk = (lane & 7) ^ srow;
  const _Float16* gA = A + (zr + m0 + wave * 8 + srow) * 512L + schk * 8;
  const _Float16* gB = W + ((long)(n0 + wave * 8 + srow)) * 512L + schk * 8;
  short* lA = &As[0][0] + wave * 512;
  short* lB = &Bs[0][0] + wave * 512;

#define STGA(buf, t, j) load_lds16(gA + (t) * 64 + (j) * (64 * 512L), lA + (buf) * 16384 + (j) * 4096)
#define STGB(buf, t, j) load_lds16(gB + (t) * 64 + (j) * (64 * 512L), lB + (buf) * 16384 + (j) * 4096)

  const int fr = lane & 15, fq = lane >> 4;
  const int wm = wave >> 2, wn = wave & 3;
  const int c0 = (fq ^ (fr & 7)) * 8;
  const int c1 = c0 ^ 32;
  const int aB0 = (wm * 128 + fr) * 64;
  const int bB0 = (wn * 64 + fr) * 64;

  f16x8 aLo[4][2], aHi[4][2], bLo[2][2], bHi[2][2];
  f32x4 acc[8][4] = {};

#define RDAL(buf, i) { aLo[i][0] = *(const f16x8*)&As[buf][aB0 + (i) * 1024 + c0]; \
                       aLo[i][1] = *(const f16x8*)&As[buf][aB0 + (i) * 1024 + c1]; }
#define RDAH(buf, i) { aHi[i][0] = *(const f16x8*)&As[buf][aB0 + ((i) + 4) * 1024 + c0]; \
                       aHi[i][1] = *(const f16x8*)&As[buf][aB0 + ((i) + 4) * 1024 + c1]; }
#define RDBL(buf, j) { bLo[j][0] = *(const f16x8*)&Bs[buf][bB0 + (j) * 1024 + c0]; \
                       bLo[j][1] = *(const f16x8*)&Bs[buf][bB0 + (j) * 1024 + c1]; }
#define RDBH(buf, j) { bHi[j][0] = *(const f16x8*)&Bs[buf][bB0 + ((j) + 2) * 1024 + c0]; \
                       bHi[j][1] = *(const f16x8*)&Bs[buf][bB0 + ((j) + 2) * 1024 + c1]; }
#define MMQ(AF, io, BF, jo) { \
  _Pragma("unroll") for (int il = 0; il < 4; il++) \
  _Pragma("unroll") for (int jl = 0; jl < 2; jl++) { \
    acc[(io) + il][(jo) + jl] = __builtin_amdgcn_mfma_f32_16x16x32_f16( \
        AF[il][0], BF[jl][0], acc[(io) + il][(jo) + jl], 0, 0, 0); \
    acc[(io) + il][(jo) + jl] = __builtin_amdgcn_mfma_f32_16x16x32_f16( \
        AF[il][1], BF[jl][1], acc[(io) + il][(jo) + jl], 0, 0, 0); } }

  STGB(0, 0, 0); STGB(0, 0, 1); STGB(0, 0, 2); STGB(0, 0, 3);
  STGA(0, 0, 0); STGA(0, 0, 1); STGA(0, 0, 2); STGA(0, 0, 3);
  STGB(1, 1, 0); STGB(1, 1, 1); STGB(1, 1, 2); STGB(1, 1, 3);
  STGA(1, 1, 0); STGA(1, 1, 1); STGA(1, 1, 2); STGA(1, 1, 3);
  VMC(8); BAR();

#pragma unroll
  for (int t = 0; t < 8; t++) {
    const int buf = t & 1;
    RDAL(buf, 0) RDAL(buf, 1) RDAL(buf, 2) RDAL(buf, 3)
    RDBL(buf, 0) RDBL(buf, 1)
    RDBH(buf, 0) RDBH(buf, 1)
    RDAH(buf, 0) RDAH(buf, 1) RDAH(buf, 2) RDAH(buf, 3)
    PR1; MMQ(aLo, 0, bLo, 0); MMQ(aLo, 0, bHi, 2); PR0;
    LGK0();
    BAR();
    if (t + 2 < 8) { STGB(buf, t + 2, 0); STGB(buf, t + 2, 1);
                     STGB(buf, t + 2, 2); STGB(buf, t + 2, 3);
                     STGA(buf, t + 2, 0); STGA(buf, t + 2, 1);
                     STGA(buf, t + 2, 2); STGA(buf, t + 2, 3); }
    PR1; MMQ(aHi, 4, bLo, 0); MMQ(aHi, 4, bHi, 2); PR0;
    if (t < 6) { VMC(8); } else if (t == 6) { VMC(0); }
    BAR();
  }

  float bv[4];
#pragma unroll
  for (int j = 0; j < 4; j++) bv[j] = bias[n0 + wn * 64 + j * 16 + fr];

  if constexpr (NOUT == 0) {
    // trunk epilogue: bias + LeakyReLU, f16 store, j-inner (write-merge)
#pragma unroll
    for (int i = 0; i < 8; i++) {
      const long row = zr + m0 + wm * 128 + i * 16 + fq * 4;
#pragma unroll
      for (int r = 0; r < 4; r++) {
        _Float16* cp = C + (row + r) * HDIM + n0 + wn * 64 + fr;
#pragma unroll
        for (int j = 0; j < 4; j++) {
          float v = acc[i][j][r] + bv[j];
          v = v > 0.f ? v : 0.2f * v;
          cp[j * 16] = (_Float16)v;
        }
      }
    }
  } else {
    // head epilogue (R11 structure): fused projection, padded plane-major
    // partials; 16-lane reduction via DPP row_shl (VALU pipe, sum -> lane fr==0).
    const int slot = ((n0 >> 8) << 2) + wn;   // 0..7
#pragma unroll
    for (int i = 0; i < 8; i++) {
#pragma unroll
      for (int r = 0; r < 4; r++) {
        const long row = zr + m0 + wm * 128 + i * 16 + fq * 4 + r;  // chunk-local
        float av[4];
#pragma unroll
        for (int j = 0; j < 4; j++) {
          float v = acc[i][j][r] + bv[j];
          av[j] = v > 0.f ? v : 0.2f * v;
        }
#pragma unroll
        for (int c = 0; c < NOUT; c++) {
          const float* Pc = P + c * 512 + n0 + wn * 64 + fr;
          float s = av[0] * Pc[0] + av[1] * Pc[16] + av[2] * Pc[32] + av[3] * Pc[48];
          s = dpp16_sum(s);
          if (fr == 0) part[(long)((CBASE + c) * 8 + slot) * PLSTR + row] = s;
        }
      }
    }
  }
#undef STGA
#undef STGB
#undef RDAL
#undef RDAH
#undef RDBL
#undef RDBH
#undef MMQ
}

// ---- finalize: sum 8 padded-plane partial slots per (row, out), final nonlinearity ----
// ob = ow32+3584: obx=ob[0..2], obr=ob[3..5], obo=ob[6]
__global__ __launch_bounds__(256)
void fin_k(const float* __restrict__ part, const float* __restrict__ ob,
           const int* __restrict__ flag, void* __restrict__ outv, long row0) {
  const long row = (long)blockIdx.x * 256 + threadIdx.x;
  float s[7];
#pragma unroll
  for (int c = 0; c < 7; c++) {
    float acc = 0.f;
#pragma unroll
    for (int sl = 0; sl < 8; sl++) acc += part[(long)(c * 8 + sl) * PLSTR + row];
    s[c] = acc;
  }
  float v[10];
#pragma unroll
  for (int c = 0; c < 3; c++) v[c] = 1.f / (1.f + __expf(-(s[c] + ob[c]))) - 0.5f;
#pragma unroll
  for (int c = 0; c < 3; c++) v[3 + c] = s[3 + c] + ob[3 + c];
  v[6] = 1.0f; v[7] = 1.0f; v[8] = 1.0f;
  v[9] = 1.f / (1.f + __expf(-(s[6] + ob[6])));
  const long ro = (row0 + row) * 10;
  if (flag[0]) {
    __hip_bfloat16* o = (__hip_bfloat16*)outv + ro;
#pragma unroll
    for (int c = 0; c < 10; c++) o[c] = __float2bfloat16(v[c]);
  } else {
    float* o = (float*)outv + ro;
#pragma unroll
    for (int c = 0; c < 10; c++) o[c] = v[c];
  }
}

extern "C" void kernel_launch(void* const* d_in, const int* in_sizes, int n_in,
                              void* d_out, int out_size, void* d_ws, size_t ws_size,
                              hipStream_t stream) {
  const void* pt    = d_in[0];
  const void* oh    = d_in[1];
  const void* z     = d_in[2];
  const void* fc1w  = d_in[3];
  const void* fc1b  = d_in[4];
  const void* fcmaw = d_in[5];
  const void* tw    = d_in[6];
  const void* twa   = d_in[7];
  const void* tba   = d_in[8];
  const void* twb   = d_in[9];
  const void* tbb   = d_in[10];
  const void* hw    = d_in[11];
  const void* hwa   = d_in[12];
  const void* hba   = d_in[13];
  const void* hwb   = d_in[14];
  const void* hbb   = d_in[15];
  const void* owx   = d_in[16];
  const void* obx   = d_in[17];
  const void* owr   = d_in[18];
  const void* obr   = d_in[19];
  // d_in[20], d_in[21] (scale head out proj) unused: clip(x,1,1) == 1
  const void* owo   = d_in[22];
  const void* obo   = d_in[23];

  char* ws = (char*)d_ws;
  _Float16* g0    = (_Float16*)(ws + 0);             // 67,108,864  (MC2 x 512 f16)
  _Float16* g1    = (_Float16*)(ws + 67108864LL);    // 67,108,864
  _Float16* X     = (_Float16*)(ws + 67108864LL);    // aliases g1 (dead before trunk0 writes g1)
  _Float16* wmodp = (_Float16*)(ws + 134217728LL);   // 14,680,064
  _Float16* Wc    = (_Float16*)(ws + 148897792LL);   // 131,072
  float* alphas   = (float*)(ws + 149028864LL);      // 57,344
  float* betas    = (float*)(ws + 149086208LL);      // 57,344
  float* fb32     = (float*)(ws + 149143552LL);      // 2,048
  int*   dflag    = (int*)  (ws + 149145600LL);      // 64
  float* ow32     = (float*)(ws + 149145664LL);      // 14,364 (3591 f32)
  float* part     = (float*)(ws + 167772160LL);      // 16,793,600 (64 planes x PLSTR f32)

  detect_k<<<1, 64, 0, stream>>>((const unsigned*)tba, dflag);
  prep_ab<<<448, 256, 0, stream>>>(z, twa, tba, twb, tbb, hwa, hba, hwb, hbb, dflag, alphas, betas);
  wmod_k<<<3584, 256, 0, stream>>>(tw, hw, dflag, alphas, wmodp);
  pack_wc<<<512, 128, 0, stream>>>(fc1w, fcmaw, fc1b, dflag, Wc, fb32);
  conv_small<<<15, 256, 0, stream>>>(owx, owr, owo, obx, obr, obo, dflag, ow32);

  dim3 gg(MCH / 128, 4, 2), gb(256);
  for (int p = 0; p < 2; p++) {
    const long prow = (long)p * MC2;
    pack_x<<<MC2 / 8, 256, 0, stream>>>(pt, oh, prow * 64, prow * 9, dflag, X);
    // fc1 via zero-padded K=128 (cols 73..127 of X and Wc are 0); same W/bias for both z
    gemm_k<<<gg, gb, 0, stream>>>(X, 128, 128, Wc, 128, 0, fb32, 0, g0);
    // trunk 0..3 (ping-pong g0 <-> g1; ends in g0)
    _Float16* fin = g0; _Float16* fout = g1;
    for (int l = 0; l < 4; l++) {
      gemm256_t<0, 0><<<512, 512, 0, stream>>>(fin, wmodp + (long)(l * 4 + p * 2) * 262144, 262144,
                                               betas + (l * 4 + p * 2) * 512, 512, fout,
                                               nullptr, nullptr);
      _Float16* t = fin; fin = fout; fout = t;
    }
    // heads: fused GEMM+projection -> padded plane-major f32 partials
    gemm256_t<3, 0><<<512, 512, 0, stream>>>(fin, wmodp + (long)(4 * 4 + p * 2) * 262144, 262144,
                                             betas + (4 * 4 + p * 2) * 512, 512, nullptr,
                                             ow32, part);
    gemm256_t<3, 3><<<512, 512, 0, stream>>>(fin, wmodp + (long)(5 * 4 + p * 2) * 262144, 262144,
                                             betas + (5 * 4 + p * 2) * 512, 512, nullptr,
                                             ow32 + 1536, part);
    gemm256_t<1, 6><<<512, 512, 0, stream>>>(fin, wmodp + (long)(6 * 4 + p * 2) * 262144, 262144,
                                             betas + (6 * 4 + p * 2) * 512, 512, nullptr,
                                             ow32 + 3072, part);
    fin_k<<<MC2 / 256, 256, 0, stream>>>(part, ow32 + 3584, dflag, d_out, prow);
  }
}